// Round 1
// baseline (106.377 us; speedup 1.0000x reference)
//
#include <hip/hip_runtime.h>
#include <hip/hip_bf16.h>
#include <math.h>

#define B 64
#define L 64
#define NPT 127
#define D 128
#define VOCAB 30000
#define LABELS 30
#define SPLIT 4
#define RPB 4
#define KP 129   // padded LDS row stride (floats) for K/V tiles

// ---------------------------------------------------------------------------
// K0: T[v][e] = sum_d emb[v][d] * Wc[d][e]   (VOCAB x D)
// Wc staged in LDS; each thread computes a 4x4 tile (4 rows x 4 cols).
// emb elements read from global (wave-broadcast, L1-resident working set).
// ---------------------------------------------------------------------------
__global__ __launch_bounds__(256) void k0_embWc(const float* __restrict__ emb,
                                                const float* __restrict__ Wc,
                                                float* __restrict__ T) {
  __shared__ float sW[D * D];  // 64 KB
  const int t = threadIdx.x;
  const int row0 = blockIdx.x * 32;
  {
    const float4* W4 = (const float4*)Wc;
    float4* sW4 = (float4*)sW;
#pragma unroll
    for (int i = 0; i < 16; ++i) sW4[t + 256 * i] = W4[t + 256 * i];
  }
  __syncthreads();
  const int rg = t >> 5;   // 0..7
  const int cg = t & 31;   // 0..31
  const int c0 = cg * 4;
  int rr[4];
#pragma unroll
  for (int i = 0; i < 4; ++i) {
    int g = row0 + rg * 4 + i;
    rr[i] = g < VOCAB ? g : VOCAB - 1;  // clamp reads, guard stores
  }
  const float* e0 = emb + (size_t)rr[0] * D;
  const float* e1 = emb + (size_t)rr[1] * D;
  const float* e2 = emb + (size_t)rr[2] * D;
  const float* e3 = emb + (size_t)rr[3] * D;
  const float4* sW4 = (const float4*)sW;
  float acc[4][4] = {};
#pragma unroll 4
  for (int k = 0; k < D; ++k) {
    float4 w = sW4[k * 32 + cg];
    float a0 = e0[k], a1 = e1[k], a2 = e2[k], a3 = e3[k];
    acc[0][0] += a0 * w.x; acc[0][1] += a0 * w.y; acc[0][2] += a0 * w.z; acc[0][3] += a0 * w.w;
    acc[1][0] += a1 * w.x; acc[1][1] += a1 * w.y; acc[1][2] += a1 * w.z; acc[1][3] += a1 * w.w;
    acc[2][0] += a2 * w.x; acc[2][1] += a2 * w.y; acc[2][2] += a2 * w.z; acc[2][3] += a2 * w.w;
    acc[3][0] += a3 * w.x; acc[3][1] += a3 * w.y; acc[3][2] += a3 * w.z; acc[3][3] += a3 * w.w;
  }
#pragma unroll
  for (int i = 0; i < 4; ++i) {
    int g = row0 + rg * 4 + i;
    if (g < VOCAB) {
      float4 o = make_float4(acc[i][0], acc[i][1], acc[i][2], acc[i][3]);
      *(float4*)&T[(size_t)g * D + c0] = o;
    }
  }
}

// ---------------------------------------------------------------------------
// K1: per (b,l): gather T rows, binary-tree subtree-sum accumulation,
// max over all 127 nodes, relu -> enc; then fused q/k/v projection.
// 128 threads = one feature dim each; RPB rows per block.
// ---------------------------------------------------------------------------
#define TREE_LEVEL(SZ)                                            \
  {                                                               \
    _Pragma("unroll")                                             \
    for (int i = 0; i < SZ; ++i) {                                \
      float e = T[(size_t)tk[(SZ - 1) + i] * D + t] + bcd;        \
      float ns = e + s[2 * i] + s[2 * i + 1];                     \
      s[i] = ns;                                                  \
      m = fmaxf(m, ns);                                           \
    }                                                             \
  }

__global__ __launch_bounds__(128) void k1_tree_qkv(
    const int* __restrict__ tokens, const float* __restrict__ T,
    const float* __restrict__ bc, const float* __restrict__ Wq,
    const float* __restrict__ Wk, const float* __restrict__ Wv,
    float* __restrict__ qb, float* __restrict__ kb, float* __restrict__ vb) {
  __shared__ int stok[RPB][NPT];
  __shared__ float sEnc[RPB][D];
  const int t = threadIdx.x;  // = feature dim d
  const int row0 = blockIdx.x * RPB;
#pragma unroll
  for (int r2 = 0; r2 < RPB; ++r2)
    if (t < NPT) stok[r2][t] = tokens[(size_t)(row0 + r2) * NPT + t];
  __syncthreads();
  const float bcd = bc[t];
  for (int r2 = 0; r2 < RPB; ++r2) {
    const int* tk = stok[r2];
    float s[64];
    float m;
    // leaves: heap nodes 63..126
#pragma unroll
    for (int i = 0; i < 64; ++i) s[i] = T[(size_t)tk[63 + i] * D + t] + bcd;
    m = s[0];
#pragma unroll
    for (int i = 1; i < 64; ++i) m = fmaxf(m, s[i]);
    TREE_LEVEL(32)
    TREE_LEVEL(16)
    TREE_LEVEL(8)
    TREE_LEVEL(4)
    TREE_LEVEL(2)
    TREE_LEVEL(1)
    sEnc[r2][t] = fmaxf(m, 0.0f);
  }
  __syncthreads();
  float aq[RPB] = {}, ak[RPB] = {}, av[RPB] = {};
  for (int k = 0; k < D; ++k) {
    float wq = Wq[k * D + t];
    float wk = Wk[k * D + t];
    float wv = Wv[k * D + t];
#pragma unroll
    for (int r2 = 0; r2 < RPB; ++r2) {
      float e = sEnc[r2][k];
      aq[r2] += e * wq;
      ak[r2] += e * wk;
      av[r2] += e * wv;
    }
  }
#pragma unroll
  for (int r2 = 0; r2 < RPB; ++r2) {
    qb[(size_t)(row0 + r2) * D + t] = aq[r2];
    kb[(size_t)(row0 + r2) * D + t] = ak[r2];
    vb[(size_t)(row0 + r2) * D + t] = av[r2];
  }
}

// ---------------------------------------------------------------------------
// K2: attention for one (batch, split of 16 q-rows). 512 threads = 8 waves,
// 2 q-rows per wave. K/V/Wo staged in LDS. Writes partial pooled-max.
// ---------------------------------------------------------------------------
__global__ __launch_bounds__(512) void k2_attn(
    const float* __restrict__ qb, const float* __restrict__ kb,
    const float* __restrict__ vb, const int* __restrict__ mask,
    const float* __restrict__ Wo, float* __restrict__ pool) {
  __shared__ float sK[L * KP];      // 33 KB
  __shared__ float sV[L * KP];      // 33 KB
  __shared__ float sWo[D * D];      // 64 KB
  __shared__ float sQ[8][D];
  __shared__ float sOr[8][D];
  __shared__ float sPool[8][D];
  const int t = threadIdx.x;
  const int w = t >> 6, lane = t & 63;
  const int b = blockIdx.x / SPLIT;
  const int sp = blockIdx.x % SPLIT;
  for (int i = t; i < L * D; i += 512) {
    int r = i >> 7, c = i & 127;
    sK[r * KP + c] = kb[(size_t)(b * L + r) * D + c];
    sV[r * KP + c] = vb[(size_t)(b * L + r) * D + c];
  }
  {
    const float4* Wo4 = (const float4*)Wo;
    float4* sWo4 = (float4*)sWo;
    for (int i = t; i < D * D / 4; i += 512) sWo4[i] = Wo4[i];
  }
  __syncthreads();
  float pm0 = -1e30f, pm1 = -1e30f;
#pragma unroll
  for (int it = 0; it < 2; ++it) {
    const int r = sp * 16 + w * 2 + it;
    // stage this wave's q row
    float2 qv = *(const float2*)&qb[(size_t)(b * L + r) * D + lane * 2];
    sQ[w][lane * 2] = qv.x;
    sQ[w][lane * 2 + 1] = qv.y;
    __syncthreads();
    // scores: lane j computes q . K[j]
    float sc = 0.f;
#pragma unroll 8
    for (int k = 0; k < D; ++k) sc += sQ[w][k] * sK[lane * KP + k];
    sc *= 0.08838834764831845f;  // 1/sqrt(128)
    if (mask[((size_t)b * L + r) * L + lane] <= 0) sc = -1e9f;
    // wave softmax over 64 lanes
    float mx = sc;
#pragma unroll
    for (int off = 32; off >= 1; off >>= 1) mx = fmaxf(mx, __shfl_xor(mx, off));
    float ex = __expf(sc - mx);
    float sm = ex;
#pragma unroll
    for (int off = 32; off >= 1; off >>= 1) sm += __shfl_xor(sm, off);
    float a = ex / sm;
    // out row: lane owns dims (lane, lane+64)
    float o0 = 0.f, o1 = 0.f;
#pragma unroll
    for (int j = 0; j < L; ++j) {
      float aj = __shfl(a, j);
      o0 += aj * sV[j * KP + lane];
      o1 += aj * sV[j * KP + lane + 64];
    }
    sOr[w][lane] = o0;
    sOr[w][lane + 64] = o1;
    __syncthreads();
    // Wo projection
    float p0 = 0.f, p1 = 0.f;
#pragma unroll 4
    for (int d = 0; d < D; ++d) {
      float od = sOr[w][d];
      p0 += od * sWo[d * D + lane];
      p1 += od * sWo[d * D + lane + 64];
    }
    pm0 = fmaxf(pm0, p0);
    pm1 = fmaxf(pm1, p1);
    __syncthreads();  // protect sQ/sOr reuse next iteration
  }
  sPool[w][lane] = pm0;
  sPool[w][lane + 64] = pm1;
  __syncthreads();
  if (t < D) {
    float pv = sPool[0][t];
#pragma unroll
    for (int i = 1; i < 8; ++i) pv = fmaxf(pv, sPool[i][t]);
    pool[(size_t)blockIdx.x * D + t] = pv;
  }
}

// ---------------------------------------------------------------------------
// K3: final pooled max over splits + logits
// ---------------------------------------------------------------------------
__global__ __launch_bounds__(128) void k3_logits(const float* __restrict__ pool,
                                                 const float* __restrict__ Wl,
                                                 const float* __restrict__ bl,
                                                 float* __restrict__ out) {
  __shared__ float sP[D];
  const int b = blockIdx.x, t = threadIdx.x;
  float pv = pool[((size_t)b * SPLIT) * D + t];
#pragma unroll
  for (int i = 1; i < SPLIT; ++i)
    pv = fmaxf(pv, pool[((size_t)b * SPLIT + i) * D + t]);
  sP[t] = pv;
  __syncthreads();
  if (t < LABELS) {
    float a = bl[t];
#pragma unroll 4
    for (int d = 0; d < D; ++d) a += sP[d] * Wl[d * LABELS + t];
    out[b * LABELS + t] = a;
  }
}

extern "C" void kernel_launch(void* const* d_in, const int* in_sizes, int n_in,
                              void* d_out, int out_size, void* d_ws, size_t ws_size,
                              hipStream_t stream) {
  const int* tokens = (const int*)d_in[0];
  const int* mask = (const int*)d_in[1];
  const float* emb = (const float*)d_in[2];
  const float* Wc = (const float*)d_in[3];
  const float* bc = (const float*)d_in[4];
  const float* Wq = (const float*)d_in[5];
  const float* Wk = (const float*)d_in[6];
  const float* Wv = (const float*)d_in[7];
  const float* Wo = (const float*)d_in[8];
  const float* Wl = (const float*)d_in[9];
  const float* bl = (const float*)d_in[10];
  float* out = (float*)d_out;

  float* T = (float*)d_ws;                    // VOCAB*D floats = 15.36 MB
  float* qb = T + (size_t)VOCAB * D;          // B*L*D
  float* kb = qb + (size_t)B * L * D;
  float* vb = kb + (size_t)B * L * D;
  float* pool = vb + (size_t)B * L * D;       // B*SPLIT*D

  hipLaunchKernelGGL(k0_embWc, dim3((VOCAB + 31) / 32), dim3(256), 0, stream,
                     emb, Wc, T);
  hipLaunchKernelGGL(k1_tree_qkv, dim3(B * L / RPB), dim3(128), 0, stream,
                     tokens, T, bc, Wq, Wk, Wv, qb, kb, vb);
  hipLaunchKernelGGL(k2_attn, dim3(B * SPLIT), dim3(512), 0, stream,
                     qb, kb, vb, mask, Wo, pool);
  hipLaunchKernelGGL(k3_logits, dim3(B), dim3(128), 0, stream,
                     pool, Wl, bl, out);
}